// Round 8
// baseline (224.430 us; speedup 1.0000x reference)
//
#include <hip/hip_runtime.h>
#include <hip/hip_bf16.h>

#define CC 256
#define NN 4096
#define CQ 32
#define LOG2E 1.4426950408889634f

using short8 = __attribute__((ext_vector_type(8))) short;
using f32x4  = __attribute__((ext_vector_type(4))) float;

static __device__ __forceinline__ short f2bf(float f) {
  __hip_bfloat16 h = __float2bfloat16(f);
  return *reinterpret_cast<short*>(&h);
}
static __device__ __forceinline__ unsigned short bf16u(float f) {
  __hip_bfloat16 h = __float2bfloat16(f);
  return *reinterpret_cast<unsigned short*>(&h);
}

// ---------------------------------------------------------------------------
// Kernel 1: QKV via MFMA, x-stationary (round-7 structure, held as control).
// ONLY change: v is stored M-INTERLEAVED within each 32-n block:
//   pair p=l15 of block: short col 2*p   = v[n_local=p]      (low)
//                        short col 2*p+1 = v[n_local=16+p]   (high)
// This matches attn's packed-P k-ordering (permuting the contraction index
// identically in P and V leaves PV exact).  Vr writes are packed b32 now.
// ---------------------------------------------------------------------------
__global__ __launch_bounds__(512, 2) void qkv_kernel(
    const float* __restrict__ x,
    const float* __restrict__ Wq, const float* __restrict__ bq,
    const float* __restrict__ Wk, const float* __restrict__ bk,
    const float* __restrict__ Wv, const float* __restrict__ bv,
    __hip_bfloat16* __restrict__ qb, __hip_bfloat16* __restrict__ kb,
    __hip_bfloat16* __restrict__ vb)
{
  const int b  = blockIdx.y;
  const int n0 = blockIdx.x * 64;
  const int tid = threadIdx.x;
  const int lane = tid & 63;
  const int w = __builtin_amdgcn_readfirstlane(tid >> 6);  // wave 0..7
  const int l15 = lane & 15, quad = lane >> 4;

  __shared__ __align__(16) short Xs[64][264];     // [n][c] bf16
  __shared__ __align__(16) short Vr[8][16][72];   // per-wave repack

  const int sn = tid & 63, cg8 = tid >> 6;
  const float* xcol = x + (size_t)b*CC*NN + n0 + sn;
#pragma unroll
  for (int it = 0; it < 4; it++) {
    int cbase = it*64 + cg8*8;
    float v[8];
#pragma unroll
    for (int j = 0; j < 8; j++) v[j] = xcol[(size_t)(cbase + j)*NN];
    short8 sv;
#pragma unroll
    for (int j = 0; j < 8; j++) sv[j] = f2bf(v[j]);
    *reinterpret_cast<short8*>(&Xs[sn][cbase]) = sv;
  }
  __syncthreads();

#define QKV_TILE(T) { \
    const int t_ = (T); \
    const float* wr; \
    { int R = t_*16 + l15; \
      if (t_ < 2)      wr = Wq + (size_t)R*CC; \
      else if (t_ < 4) wr = Wk + (size_t)(R-32)*CC; \
      else             wr = Wv + (size_t)(R-64)*CC; } \
    short8 Af[8]; \
    _Pragma("unroll") \
    for (int kc = 0; kc < 8; kc++) { \
      float4 fa = *(const float4*)(wr + kc*32 + quad*8); \
      float4 fc = *(const float4*)(wr + kc*32 + quad*8 + 4); \
      short8 o; \
      o[0]=f2bf(fa.x); o[1]=f2bf(fa.y); o[2]=f2bf(fa.z); o[3]=f2bf(fa.w); \
      o[4]=f2bf(fc.x); o[5]=f2bf(fc.y); o[6]=f2bf(fc.z); o[7]=f2bf(fc.w); \
      Af[kc] = o; \
    } \
    f32x4 ac0 = {0.f,0.f,0.f,0.f}, ac1 = {0.f,0.f,0.f,0.f}; \
    f32x4 ac2 = {0.f,0.f,0.f,0.f}, ac3 = {0.f,0.f,0.f,0.f}; \
    _Pragma("unroll") \
    for (int kc = 0; kc < 8; kc++) { \
      short8 B0 = *(const short8*)(&Xs[     l15][kc*32 + quad*8]); \
      short8 B1 = *(const short8*)(&Xs[16 + l15][kc*32 + quad*8]); \
      short8 B2 = *(const short8*)(&Xs[32 + l15][kc*32 + quad*8]); \
      short8 B3 = *(const short8*)(&Xs[48 + l15][kc*32 + quad*8]); \
      ac0 = __builtin_amdgcn_mfma_f32_16x16x32_bf16(Af[kc], B0, ac0, 0,0,0); \
      ac1 = __builtin_amdgcn_mfma_f32_16x16x32_bf16(Af[kc], B1, ac1, 0,0,0); \
      ac2 = __builtin_amdgcn_mfma_f32_16x16x32_bf16(Af[kc], B2, ac2, 0,0,0); \
      ac3 = __builtin_amdgcn_mfma_f32_16x16x32_bf16(Af[kc], B3, ac3, 0,0,0); \
    } \
    if (t_ < 2) { \
      int d0 = t_*16; \
      _Pragma("unroll") \
      for (int r = 0; r < 4; r++) { \
        int d = d0 + quad*4 + r; float bb = bq[d]; \
        qb[(size_t)b*NN*CQ + (size_t)(n0      + l15)*CQ + d] = __float2bfloat16(LOG2E*(ac0[r] + bb)); \
        qb[(size_t)b*NN*CQ + (size_t)(n0 + 16 + l15)*CQ + d] = __float2bfloat16(LOG2E*(ac1[r] + bb)); \
        qb[(size_t)b*NN*CQ + (size_t)(n0 + 32 + l15)*CQ + d] = __float2bfloat16(LOG2E*(ac2[r] + bb)); \
        qb[(size_t)b*NN*CQ + (size_t)(n0 + 48 + l15)*CQ + d] = __float2bfloat16(LOG2E*(ac3[r] + bb)); \
      } \
    } else if (t_ < 4) { \
      int d0 = (t_-2)*16; \
      _Pragma("unroll") \
      for (int r = 0; r < 4; r++) { \
        int d = d0 + quad*4 + r; float bb = bk[d]; \
        kb[(size_t)b*NN*CQ + (size_t)(n0      + l15)*CQ + d] = __float2bfloat16(ac0[r] + bb); \
        kb[(size_t)b*NN*CQ + (size_t)(n0 + 16 + l15)*CQ + d] = __float2bfloat16(ac1[r] + bb); \
        kb[(size_t)b*NN*CQ + (size_t)(n0 + 32 + l15)*CQ + d] = __float2bfloat16(ac2[r] + bb); \
        kb[(size_t)b*NN*CQ + (size_t)(n0 + 48 + l15)*CQ + d] = __float2bfloat16(ac3[r] + bb); \
      } \
    } else { \
      int rv0 = (t_-4)*16; \
      unsigned int* vru = reinterpret_cast<unsigned int*>(&Vr[w][0][0]); /* [16][36] */ \
      _Pragma("unroll") \
      for (int r = 0; r < 4; r++) { \
        float bb = bv[rv0 + quad*4 + r]; \
        unsigned int p01 = (unsigned int)bf16u(ac0[r] + bb) | ((unsigned int)bf16u(ac1[r] + bb) << 16); \
        unsigned int p23 = (unsigned int)bf16u(ac2[r] + bb) | ((unsigned int)bf16u(ac3[r] + bb) << 16); \
        vru[(quad*4 + r)*36 + l15]      = p01;  /* block0: shorts 2*l15, 2*l15+1 */ \
        vru[(quad*4 + r)*36 + 16 + l15] = p23;  /* block1: shorts 32+2*l15, ...  */ \
      } \
      int row = lane >> 2, cb = (lane & 3)*16; \
      short8 t0 = *(const short8*)(&Vr[w][row][cb]); \
      short8 t1 = *(const short8*)(&Vr[w][row][cb + 8]); \
      *(short8*)(vb + ((size_t)b*CC + rv0 + row)*NN + n0 + cb)     = t0; \
      *(short8*)(vb + ((size_t)b*CC + rv0 + row)*NN + n0 + cb + 8) = t1; \
    } }

  QKV_TILE(2*w);
  QKV_TILE(2*w + 1);
  if (w < 4) { QKV_TILE(16 + w); }
#undef QKV_TILE
}

// ---------------------------------------------------------------------------
// Kernel 2: O = softmax(QK^T) V, epilogue gamma*O + x.
// 512 threads / 8 waves, grid 512 (32-n blocks) + __launch_bounds__(512,4)
// => 2 blocks/CU, 4 waves/SIMD.  m-tile 128, 32 iters, ONE barrier/iter.
// V never touches LDS: PV A-frags loaded global->reg from L2 (issued BEFORE
// the barrier so the compiler's vmcnt(0) drain overlaps the barrier wait).
// P stored in LDS as packed bf16x2 uints, m-interleaved (matches vb layout):
//   PsU[pb][n 0..31][u = mq*16 + l15]  (stride 68 uints; writes 2-way free,
//   b128 ap reads uniform 8 lanes/4-bank tile = b128 floor, free).
// Waves: S-role (sg=w&1, mq=w>>1): 16n x 32m scores; PV-role: c-strip w*32,
// all 32 n, K=128/iter -> acc[2][2] (16 regs, const subscripts only).
// ---------------------------------------------------------------------------
__global__ __launch_bounds__(512, 4) void attn_kernel(
    const __hip_bfloat16* __restrict__ qb, const __hip_bfloat16* __restrict__ kb,
    const __hip_bfloat16* __restrict__ vb,
    const float* __restrict__ x, const float* __restrict__ gamma,
    float* __restrict__ out)
{
  const int Bk = blockIdx.x;                          // 0..511
  const int b  = (Bk & 7) >> 1;                       // 2 XCDs per batch
  const int n0 = ((Bk >> 3)*2 + (Bk & 1)) * 32;       // n-tile 0..127
  const int tid = threadIdx.x;
  const int lane = tid & 63;
  const int w = __builtin_amdgcn_readfirstlane(tid >> 6);   // 0..7
  const int sg = w & 1;                                // S n-group
  const int mq = w >> 1;                               // S m-quarter 0..3
  const int l15 = lane & 15, quad = lane >> 4;

  __shared__ unsigned int PsU[2][32][68];              // 17408 B
  __shared__ float Lbuf[4][32];

  const short* qbase = (const short*)qb + (size_t)b*NN*CQ;
  const short* kbase = (const short*)kb + (size_t)b*NN*CQ;
  const short* vbase = (const short*)vb + (size_t)b*CC*NN;

  short8 aq = *(const short8*)(qbase + (size_t)(n0 + sg*16 + l15)*CQ + quad*8);

  f32x4 acc[2][2];
#pragma unroll
  for (int cg = 0; cg < 2; cg++)
#pragma unroll
    for (int ng = 0; ng < 2; ng++) acc[cg][ng] = (f32x4){0.f,0.f,0.f,0.f};
  float lsum[4] = {0.f,0.f,0.f,0.f};

  for (int T = 0; T < 32; T++) {
    const int pb = T & 1;
    const int mT = T*128 + mq*32;

    // K frags for this wave's m-quarter (L2-hot, ~256 KB/batch)
    short8 kf0 = *(const short8*)(kbase + (size_t)(mT      + l15)*CQ + quad*8);
    short8 kf1 = *(const short8*)(kbase + (size_t)(mT + 16 + l15)*CQ + quad*8);

    f32x4 z = {0.f,0.f,0.f,0.f};
    f32x4 S0 = __builtin_amdgcn_mfma_f32_16x16x32_bf16(aq, kf0, z, 0,0,0);
    f32x4 S1 = __builtin_amdgcn_mfma_f32_16x16x32_bf16(aq, kf1, z, 0,0,0);
#pragma unroll
    for (int r = 0; r < 4; r++) {
      float e0 = __builtin_amdgcn_exp2f(S0[r]);
      float e1 = __builtin_amdgcn_exp2f(S1[r]);
      lsum[r] += e0 + e1;
      PsU[pb][sg*16 + quad*4 + r][mq*16 + l15] =
          (unsigned int)bf16u(e0) | ((unsigned int)bf16u(e1) << 16);
    }

    // V A-frags for this tile, issued BEFORE the barrier: the vmcnt(0)
    // drain the compiler emits for __syncthreads overlaps the barrier wait.
    short8 av[2][4];
#pragma unroll
    for (int cg = 0; cg < 2; cg++)
#pragma unroll
      for (int kq = 0; kq < 4; kq++)
        av[cg][kq] = *(const short8*)(
            vbase + (size_t)(w*32 + cg*16 + l15)*NN + T*128 + kq*32 + quad*8);

    __syncthreads();   // publishes PsU[pb] (the only cross-wave data)

    short8 ap[2][4];
#pragma unroll
    for (int ng = 0; ng < 2; ng++)
#pragma unroll
      for (int kq = 0; kq < 4; kq++)
        ap[ng][kq] = *(const short8*)(&PsU[pb][ng*16 + l15][kq*16 + quad*4]);

#pragma unroll
    for (int cg = 0; cg < 2; cg++)
#pragma unroll
      for (int ng = 0; ng < 2; ng++)
#pragma unroll
        for (int kq = 0; kq < 4; kq++)
          acc[cg][ng] = __builtin_amdgcn_mfma_f32_16x16x32_bf16(
              av[cg][kq], ap[ng][kq], acc[cg][ng], 0,0,0);
    // no trailing barrier: next iter writes the OTHER PsU buffer; the
    // barrier at iter T+1 orders write(T+2,pb) after all reads(T,pb).
  }

  // ---- row sums: reduce over the quad's 16 lanes, publish per m-quarter ----
#pragma unroll
  for (int r = 0; r < 4; r++) {
    float s = lsum[r];
    s += __shfl_xor(s, 1); s += __shfl_xor(s, 2);
    s += __shfl_xor(s, 4); s += __shfl_xor(s, 8);
    if (l15 == 0) Lbuf[mq][sg*16 + quad*4 + r] = s;
  }
  __syncthreads();

  // ---- epilogue: acc[cg][ng] = O^T[c = w*32+cg*16+quad*4+r][n = ng*16+l15]
  const float gm = gamma[0];
  float Lv[2];
#pragma unroll
  for (int ng = 0; ng < 2; ng++)
    Lv[ng] = 1.0f / (Lbuf[0][ng*16 + l15] + Lbuf[1][ng*16 + l15] +
                     Lbuf[2][ng*16 + l15] + Lbuf[3][ng*16 + l15]);
#pragma unroll
  for (int cg = 0; cg < 2; cg++) {
#pragma unroll
    for (int ng = 0; ng < 2; ng++) {
#pragma unroll
      for (int r = 0; r < 4; r++) {
        size_t idx = ((size_t)b*CC + w*32 + cg*16 + quad*4 + r)*NN + n0 + ng*16 + l15;
        out[idx] = gm * acc[cg][ng][r] * Lv[ng] + x[idx];
      }
    }
  }
}

// ---------------------------------------------------------------------------
extern "C" void kernel_launch(void* const* d_in, const int* in_sizes, int n_in,
                              void* d_out, int out_size, void* d_ws, size_t ws_size,
                              hipStream_t stream) {
  const float* x     = (const float*)d_in[0];
  const float* Wq    = (const float*)d_in[1];
  const float* bq    = (const float*)d_in[2];
  const float* Wk    = (const float*)d_in[3];
  const float* bk    = (const float*)d_in[4];
  const float* Wv    = (const float*)d_in[5];
  const float* bv    = (const float*)d_in[6];
  const float* gamma = (const float*)d_in[7];
  float* out = (float*)d_out;

  char* ws = (char*)d_ws;
  if (ws_size < (10u << 20)) return;
  __hip_bfloat16* qb = (__hip_bfloat16*)(ws);                 // [B][N][32]  1 MB
  __hip_bfloat16* kb = (__hip_bfloat16*)(ws + (1u << 20));    // [B][N][32]  1 MB
  __hip_bfloat16* vb = (__hip_bfloat16*)(ws + (2u << 20));    // [B][C][N] (m-interleaved) 8 MB

  qkv_kernel<<<dim3(64, 4), 512, 0, stream>>>(x, Wq, bq, Wk, bk, Wv, bv, qb, kb, vb);
  attn_kernel<<<dim3(512), 512, 0, stream>>>(qb, kb, vb, x, gamma, out);
}

// Round 9
// 175.144 us; speedup vs baseline: 1.2814x; 1.2814x over previous
//
#include <hip/hip_runtime.h>
#include <hip/hip_bf16.h>

#define CC 256
#define NN 4096
#define CQ 32
#define LOG2E 1.4426950408889634f

using short8 = __attribute__((ext_vector_type(8))) short;
using f32x16 = __attribute__((ext_vector_type(16))) float;

static __device__ __forceinline__ short f2bf(float f) {
  __hip_bfloat16 h = __float2bfloat16(f);
  return *reinterpret_cast<short*>(&h);
}

// ---------------------------------------------------------------------------
// Kernel 1: QKV via 32x32x16 MFMA, x-stationary.  256 threads (4 waves),
// grid 128x4 = 512 blocks => 2+ blocks/CU (cross-block latency cover).
// Stage x[256c x 32n] -> LDS bf16 [n][c].  10 r-tiles of 32 rows
// (t0=q, t1=k, t2..9=v); wave w does tiles {w, 4+w} (+ {8+w} for w<2).
// A-frags: W fp32->bf16 in-register (W L2-hot).  All outputs repacked via
// wave-private LDS Tr -> fully coalesced 16B stores.
// Layouts: A[r=lane&31][k=(lane>>5)*8+j]; B[k][n=lane&31] (k contiguous at
// fixed n in Xs[n][c]); D[row=(reg&3)+8*(reg>>2)+4*(lane>>5)][col=lane&31].
// ---------------------------------------------------------------------------
__global__ __launch_bounds__(256, 4) void qkv_kernel(
    const float* __restrict__ x,
    const float* __restrict__ Wq, const float* __restrict__ bq,
    const float* __restrict__ Wk, const float* __restrict__ bk,
    const float* __restrict__ Wv, const float* __restrict__ bv,
    __hip_bfloat16* __restrict__ qb, __hip_bfloat16* __restrict__ kb,
    __hip_bfloat16* __restrict__ vb)
{
  const int b  = blockIdx.y;
  const int n0 = blockIdx.x * 32;
  const int tid = threadIdx.x;
  const int lane = tid & 63;
  const int w = __builtin_amdgcn_readfirstlane(tid >> 6);  // wave 0..3
  const int l31 = lane & 31, h = lane >> 5;

  __shared__ __align__(16) short Xs[32][264];   // [n][c] bf16, 16.5 KB
  __shared__ __align__(16) short Tr[4][32][36]; // per-wave repack, 9 KB

  // ---- stage x tile ----
  const int sn = tid & 31, cg = tid >> 5;       // n, c-group
  const float* xcol = x + (size_t)b*CC*NN + n0 + sn;
#pragma unroll
  for (int it = 0; it < 4; it++) {
    int cbase = it*64 + cg*8;
    float v[8];
#pragma unroll
    for (int j = 0; j < 8; j++) v[j] = xcol[(size_t)(cbase + j)*NN];
    short8 sv;
#pragma unroll
    for (int j = 0; j < 8; j++) sv[j] = f2bf(v[j]);
    *reinterpret_cast<short8*>(&Xs[sn][cbase]) = sv;
  }
  __syncthreads();

#define QKV_TILE(RT) { \
    const int rt = (RT); \
    const float* wr; \
    if (rt == 0)      wr = Wq + (size_t)l31*CC; \
    else if (rt == 1) wr = Wk + (size_t)l31*CC; \
    else              wr = Wv + (size_t)((rt-2)*32 + l31)*CC; \
    f32x16 acc = {}; \
    _Pragma("unroll") \
    for (int kc = 0; kc < 16; kc++) { \
      float4 fa = *(const float4*)(wr + kc*16 + h*8); \
      float4 fc = *(const float4*)(wr + kc*16 + h*8 + 4); \
      short8 af; \
      af[0]=f2bf(fa.x); af[1]=f2bf(fa.y); af[2]=f2bf(fa.z); af[3]=f2bf(fa.w); \
      af[4]=f2bf(fc.x); af[5]=f2bf(fc.y); af[6]=f2bf(fc.z); af[7]=f2bf(fc.w); \
      short8 bf = *(const short8*)(&Xs[l31][kc*16 + h*8]); \
      acc = __builtin_amdgcn_mfma_f32_32x32x16_bf16(af, bf, acc, 0, 0, 0); \
    } \
    /* D -> Tr; q/k transposed to [n][d], v row-major [c][n] */ \
    _Pragma("unroll") \
    for (int e = 0; e < 16; e++) { \
      int row = (e & 3) + 8*(e >> 2) + 4*h; \
      if (rt == 0)      Tr[w][l31][row] = f2bf(LOG2E*(acc[e] + bq[row])); \
      else if (rt == 1) Tr[w][l31][row] = f2bf(acc[e] + bk[row]); \
      else              Tr[w][row][l31] = f2bf(acc[e] + bv[(rt-2)*32 + row]); \
    } \
    /* wave-private LDS: in-order, no barrier; coalesced readback+store */ \
    _Pragma("unroll") \
    for (int g = 0; g < 2; g++) { \
      int row = g*16 + (lane >> 2), ch = lane & 3; \
      short8 t = *(const short8*)(&Tr[w][row][ch*8]); \
      if (rt == 0) \
        *(short8*)(qb + ((size_t)b*NN + n0 + row)*CQ + ch*8) = t; \
      else if (rt == 1) \
        *(short8*)(kb + ((size_t)b*NN + n0 + row)*CQ + ch*8) = t; \
      else \
        *(short8*)(vb + ((size_t)b*CC + (rt-2)*32 + row)*NN + n0 + ch*8) = t; \
    } }

  QKV_TILE(w);
  QKV_TILE(4 + w);
  if (w < 2) { QKV_TILE(8 + w); }
#undef QKV_TILE
}

// ---------------------------------------------------------------------------
// Kernel 2: O = softmax(QK^T) V via 32x32x16 MFMA.  512 threads / 8 waves,
// grid 256 (64-n blocks).  m-tile 128, 32 iters, ONE barrier/iter.
// Wave (sg=w&1, mq=w>>1): S-tile 32n x 32m (2 MFMAs, K=32); exp2 -> Pt LDS
// (pitch 136 shorts: write rows n,n+4 land on disjoint 16-bank sets; b128
// reads spread 8 accesses/bank, even).  PV: wave owns c-strip w*32, V loaded
// global->reg (natural [c][m], 8 x b128/iter, L2-resident 2MB/batch), 16
// MFMAs into two f32x16 accs (no dynamic acc indexing).  K prefetched one
// tile ahead.  Pt double-buffered: the single barrier both publishes Pt(T)
// and (one iter later) protects its reuse.
// ---------------------------------------------------------------------------
__global__ __launch_bounds__(512, 2) void attn_kernel(
    const __hip_bfloat16* __restrict__ qb, const __hip_bfloat16* __restrict__ kb,
    const __hip_bfloat16* __restrict__ vb,
    const float* __restrict__ x, const float* __restrict__ gamma,
    float* __restrict__ out)
{
  const int Bk = blockIdx.x;                          // 0..255
  const int b  = (Bk & 7) >> 1;                       // 2 XCDs per batch
  const int n0 = ((Bk >> 3)*2 + (Bk & 1)) * 64;       // n-tile 0..63
  const int tid = threadIdx.x;
  const int lane = tid & 63;
  const int w = __builtin_amdgcn_readfirstlane(tid >> 6);   // 0..7
  const int sg = w & 1;                                // S n-half
  const int mq = w >> 1;                               // S m-quarter 0..3
  const int l31 = lane & 31, h = lane >> 5;

  __shared__ __align__(16) short Pt[2][64][136];       // 34816 B
  __shared__ float Lbuf[4][64];

  const short* qbase = (const short*)qb + (size_t)b*NN*CQ;
  const short* kbase = (const short*)kb + (size_t)b*NN*CQ;
  const short* vbase = (const short*)vb + (size_t)b*CC*NN;

  // Q A-frags (kept all kernel): A[n=l31][k=kc*16+h*8+j]
  short8 aq0 = *(const short8*)(qbase + (size_t)(n0 + sg*32 + l31)*CQ + h*8);
  short8 aq1 = *(const short8*)(qbase + (size_t)(n0 + sg*32 + l31)*CQ + 16 + h*8);

  // K B-frags for tile 0: B[k][m=l31] = K[m][k], k contiguous in kb row
  short8 kf0 = *(const short8*)(kbase + (size_t)(mq*32 + l31)*CQ + h*8);
  short8 kf1 = *(const short8*)(kbase + (size_t)(mq*32 + l31)*CQ + 16 + h*8);

  f32x16 acc0 = {}, acc1 = {};
  float lsum[16];
#pragma unroll
  for (int e = 0; e < 16; e++) lsum[e] = 0.0f;

  const short* vstrip = vbase + (size_t)(w*32 + l31)*NN + h*8;

  for (int T = 0; T < 32; T++) {
    const int pb = T & 1;

    // V A-frags for tile T (global->reg; arrive during S/exp/barrier)
    short8 av0 = *(const short8*)(vstrip + T*128 +   0);
    short8 av1 = *(const short8*)(vstrip + T*128 +  16);
    short8 av2 = *(const short8*)(vstrip + T*128 +  32);
    short8 av3 = *(const short8*)(vstrip + T*128 +  48);
    short8 av4 = *(const short8*)(vstrip + T*128 +  64);
    short8 av5 = *(const short8*)(vstrip + T*128 +  80);
    short8 av6 = *(const short8*)(vstrip + T*128 +  96);
    short8 av7 = *(const short8*)(vstrip + T*128 + 112);

    // S' = (log2e q) k^T : 32n x 32m
    f32x16 z = {};
    f32x16 S = __builtin_amdgcn_mfma_f32_32x32x16_bf16(aq0, kf0, z, 0, 0, 0);
    S = __builtin_amdgcn_mfma_f32_32x32x16_bf16(aq1, kf1, S, 0, 0, 0);

    // prefetch K for tile T+1
    if (T < 31) {
      kf0 = *(const short8*)(kbase + (size_t)((T+1)*128 + mq*32 + l31)*CQ + h*8);
      kf1 = *(const short8*)(kbase + (size_t)((T+1)*128 + mq*32 + l31)*CQ + 16 + h*8);
    }

    // P = exp2(S') -> Pt[pb][n][m], row sums accumulated in regs
#pragma unroll
    for (int e = 0; e < 16; e++) {
      float p = __builtin_amdgcn_exp2f(S[e]);
      lsum[e] += p;
      int nrow = sg*32 + (e & 3) + 8*(e >> 2) + 4*h;
      Pt[pb][nrow][mq*32 + l31] = f2bf(p);
    }

    __syncthreads();   // publishes Pt[pb] (drains av/kf loads too -- overlap)

    // PV: acc[ng] += V_strip(32c x 16k) * P^T(16k x 32n), 8 k-chunks
#pragma unroll
    for (int kc = 0; kc < 8; kc++) {
      short8 av;
      if (kc == 0) av = av0; else if (kc == 1) av = av1;
      else if (kc == 2) av = av2; else if (kc == 3) av = av3;
      else if (kc == 4) av = av4; else if (kc == 5) av = av5;
      else if (kc == 6) av = av6; else av = av7;
      short8 bp0 = *(const short8*)(&Pt[pb][     l31][kc*16 + h*8]);
      short8 bp1 = *(const short8*)(&Pt[pb][32 + l31][kc*16 + h*8]);
      acc0 = __builtin_amdgcn_mfma_f32_32x32x16_bf16(av, bp0, acc0, 0, 0, 0);
      acc1 = __builtin_amdgcn_mfma_f32_32x32x16_bf16(av, bp1, acc1, 0, 0, 0);
    }
    // no trailing barrier: next iter writes the other Pt buffer; barrier(T+1)
    // orders all reads of Pt[pb](T) before writes at T+2.
  }

  // ---- row sums: reduce across the 32-lane m-group, publish per m-quarter
#pragma unroll
  for (int e = 0; e < 16; e++) {
    float s = lsum[e];
    s += __shfl_xor(s, 1); s += __shfl_xor(s, 2);
    s += __shfl_xor(s, 4); s += __shfl_xor(s, 8); s += __shfl_xor(s, 16);
    if (l31 == 0) {
      int nrow = sg*32 + (e & 3) + 8*(e >> 2) + 4*h;
      Lbuf[mq][nrow] = s;
    }
  }
  __syncthreads();

  // ---- epilogue: acc[ng][e] = O^T[c = w*32 + rowD][n = n0 + ng*32 + l31]
  const float gm = gamma[0];
  float Lv0 = 1.0f / (Lbuf[0][l31]      + Lbuf[1][l31]      + Lbuf[2][l31]      + Lbuf[3][l31]);
  float Lv1 = 1.0f / (Lbuf[0][32 + l31] + Lbuf[1][32 + l31] + Lbuf[2][32 + l31] + Lbuf[3][32 + l31]);
#pragma unroll
  for (int e = 0; e < 16; e++) {
    int crow = w*32 + (e & 3) + 8*(e >> 2) + 4*h;
    size_t i0 = ((size_t)b*CC + crow)*NN + n0 + l31;
    out[i0]      = gm * acc0[e] * Lv0 + x[i0];
    out[i0 + 32] = gm * acc1[e] * Lv1 + x[i0 + 32];
  }
}

// ---------------------------------------------------------------------------
extern "C" void kernel_launch(void* const* d_in, const int* in_sizes, int n_in,
                              void* d_out, int out_size, void* d_ws, size_t ws_size,
                              hipStream_t stream) {
  const float* x     = (const float*)d_in[0];
  const float* Wq    = (const float*)d_in[1];
  const float* bq    = (const float*)d_in[2];
  const float* Wk    = (const float*)d_in[3];
  const float* bk    = (const float*)d_in[4];
  const float* Wv    = (const float*)d_in[5];
  const float* bv    = (const float*)d_in[6];
  const float* gamma = (const float*)d_in[7];
  float* out = (float*)d_out;

  char* ws = (char*)d_ws;
  if (ws_size < (10u << 20)) return;
  __hip_bfloat16* qb = (__hip_bfloat16*)(ws);                 // [B][N][32]  1 MB
  __hip_bfloat16* kb = (__hip_bfloat16*)(ws + (1u << 20));    // [B][N][32]  1 MB
  __hip_bfloat16* vb = (__hip_bfloat16*)(ws + (2u << 20));    // [B][C][N]   8 MB

  qkv_kernel<<<dim3(128, 4), 256, 0, stream>>>(x, Wq, bq, Wk, bk, Wv, bv, qb, kb, vb);
  attn_kernel<<<dim3(256), 512, 0, stream>>>(qb, kb, vb, x, gamma, out);
}